// Round 1
// baseline (49.916 us; speedup 1.0000x reference)
//
#include <hip/hip_runtime.h>

typedef float f32x4 __attribute__((ext_vector_type(4)));
typedef short s16x8 __attribute__((ext_vector_type(8)));

#define DIN 24
#define DH1 64
#define DH2 128
#define DOUT 64
#define H1PAD 80   // bf16 elems per h1 row in LDS (160B, 16B-aligned rows)
#define H2PAD 136  // bf16 elems per h2 row in LDS (272B, 16B-aligned rows)

// f32 -> bf16 bits, round-to-nearest-even
static __device__ __forceinline__ unsigned short f2bf(float f) {
    unsigned int u = __builtin_bit_cast(unsigned int, f);
    u += 0x7FFFu + ((u >> 16) & 1u);
    return (unsigned short)(u >> 16);
}

__global__ __launch_bounds__(256, 2) void linenet_mfma(
    const float* __restrict__ in,
    const float* __restrict__ W1, const float* __restrict__ b1,
    const float* __restrict__ W2, const float* __restrict__ b2,
    const float* __restrict__ W3, const float* __restrict__ b3,
    float* __restrict__ out, int M)
{
    // W3 fragments, built once per block: [ks*4+nt][lane][j] bf16 -> 16KB
    __shared__ __align__(16) unsigned short w3lds[16 * 64 * 8];
    // per-wave private h1/h2 staging (bf16), padded rows for bank spread
    __shared__ __align__(16) unsigned short h1lds[4][16 * H1PAD];
    __shared__ __align__(16) unsigned short h2lds[4][16 * H2PAD];

    const int tid = threadIdx.x;

    // ---- build W3 fragment table in LDS (once per block) ----
    for (int it = tid; it < 16 * 64; it += 256) {
        const int frag = it >> 6;          // ks*4 + nt
        const int ln   = it & 63;
        const int ks   = frag >> 2, nt = frag & 3;
        const int g    = ln >> 4,   c  = ln & 15;
        #pragma unroll
        for (int j = 0; j < 8; ++j) {
            const int k = 32 * ks + 8 * g + j;             // k < 128
            w3lds[it * 8 + j] = f2bf(W3[k * DOUT + nt * 16 + c]);
        }
    }
    __syncthreads();

    const int wave = tid >> 6, lane = tid & 63;
    const int gl = lane >> 4, cl = lane & 15;

    // ---- per-wave VGPR-resident weight fragments ----
    // B-frag layout for 16x16x32: lane holds col n = 16*nt + (lane&15),
    // k = 8*(lane>>4) + j  (8 contiguous k per lane).
    s16x8 w1f[4];
    #pragma unroll
    for (int nt = 0; nt < 4; ++nt) {
        #pragma unroll
        for (int j = 0; j < 8; ++j) {
            const int k = 8 * gl + j;
            w1f[nt][j] = (k < DIN) ? (short)f2bf(W1[k * DH1 + nt * 16 + cl]) : (short)0;
        }
    }
    s16x8 w2f[2][8];
    #pragma unroll
    for (int ks = 0; ks < 2; ++ks)
        #pragma unroll
        for (int nt = 0; nt < 8; ++nt)
            #pragma unroll
            for (int j = 0; j < 8; ++j)
                w2f[ks][nt][j] = (short)f2bf(W2[(32 * ks + 8 * gl + j) * DH2 + nt * 16 + cl]);

    float b1v[4], b2v[8], b3v[4];
    #pragma unroll
    for (int nt = 0; nt < 4; ++nt) b1v[nt] = b1[nt * 16 + cl];
    #pragma unroll
    for (int nt = 0; nt < 8; ++nt) b2v[nt] = b2[nt * 16 + cl];
    #pragma unroll
    for (int nt = 0; nt < 4; ++nt) b3v[nt] = b3[nt * 16 + cl];

    unsigned short* const h1p = &h1lds[wave][0];
    unsigned short* const h2p = &h2lds[wave][0];

    const int NT = M / 16;                  // 16-row tiles
    const int nw = (int)gridDim.x * 4;      // total waves
    int t = (int)blockIdx.x * 4 + wave;
    if (t >= NT) return;

    // A-frag input offset: lane reads row (lane&15), 8 consecutive k at 8*gl.
    // gl==3 lanes (k=24..31) read valid-but-unused data; their w1f is all-zero,
    // and finite*0 == 0, so the result is correct without masking.
    const int goff = (gl < 3) ? 8 * gl : 16;
    const int loff = cl * DIN + goff;

    // prefetch first tile
    f32x4 pf0, pf1;
    {
        const float* p = in + (size_t)t * (16 * DIN) + loff;
        pf0 = *(const f32x4*)p;
        pf1 = *(const f32x4*)(p + 4);
    }

    f32x4 zac = {0.f, 0.f, 0.f, 0.f};

    while (t < NT) {
        // ---- A1 fragment from prefetched registers ----
        s16x8 a1;
        #pragma unroll
        for (int j = 0; j < 4; ++j) {
            a1[j]     = (short)f2bf(pf0[j]);
            a1[4 + j] = (short)f2bf(pf1[j]);
        }

        // ---- issue next tile's global loads early (hide HBM latency) ----
        const int tn = t + nw;
        {
            const int tc = (tn < NT) ? tn : t;  // clamp (redundant reload on last iter)
            const float* p = in + (size_t)tc * (16 * DIN) + loff;
            pf0 = *(const f32x4*)p;
            pf1 = *(const f32x4*)(p + 4);
        }

        // ---- layer 1: [16x24]x[24x64] ----
        f32x4 acc1[4];
        #pragma unroll
        for (int nt = 0; nt < 4; ++nt)
            acc1[nt] = __builtin_amdgcn_mfma_f32_16x16x32_bf16(a1, w1f[nt], zac, 0, 0, 0);

        // h1 = relu(acc1 + b1) -> LDS bf16  (D layout: row = 4*gl + r, col = 16*nt + cl)
        #pragma unroll
        for (int nt = 0; nt < 4; ++nt)
            #pragma unroll
            for (int r = 0; r < 4; ++r) {
                float v = fmaxf(acc1[nt][r] + b1v[nt], 0.f);
                h1p[(4 * gl + r) * H1PAD + nt * 16 + cl] = f2bf(v);
            }

        // ---- layer 2: [16x64]x[64x128] ----
        s16x8 a2[2];
        #pragma unroll
        for (int ks = 0; ks < 2; ++ks)
            a2[ks] = *(const s16x8*)&h1p[cl * H1PAD + 32 * ks + 8 * gl];

        f32x4 acc2[8];
        #pragma unroll
        for (int nt = 0; nt < 8; ++nt)
            acc2[nt] = __builtin_amdgcn_mfma_f32_16x16x32_bf16(a2[0], w2f[0][nt], zac, 0, 0, 0);
        #pragma unroll
        for (int nt = 0; nt < 8; ++nt)
            acc2[nt] = __builtin_amdgcn_mfma_f32_16x16x32_bf16(a2[1], w2f[1][nt], acc2[nt], 0, 0, 0);

        #pragma unroll
        for (int nt = 0; nt < 8; ++nt)
            #pragma unroll
            for (int r = 0; r < 4; ++r) {
                float v = fmaxf(acc2[nt][r] + b2v[nt], 0.f);
                h2p[(4 * gl + r) * H2PAD + nt * 16 + cl] = f2bf(v);
            }

        // ---- layer 3: [16x128]x[128x64] ----
        f32x4 acc3[4];
        #pragma unroll
        for (int ks = 0; ks < 4; ++ks) {
            const s16x8 a3 = *(const s16x8*)&h2p[cl * H2PAD + 32 * ks + 8 * gl];
            #pragma unroll
            for (int nt = 0; nt < 4; ++nt) {
                const s16x8 wf = *(const s16x8*)&w3lds[((ks * 4 + nt) * 64 + lane) * 8];
                acc3[nt] = __builtin_amdgcn_mfma_f32_16x16x32_bf16(
                    a3, wf, (ks == 0) ? zac : acc3[nt], 0, 0, 0);
            }
        }

        // ---- epilogue: relu + store (4x64B segments per store instr) ----
        float* const ob = out + (size_t)t * (16 * DOUT);
        #pragma unroll
        for (int nt = 0; nt < 4; ++nt)
            #pragma unroll
            for (int r = 0; r < 4; ++r) {
                float v = fmaxf(acc3[nt][r] + b3v[nt], 0.f);
                ob[(4 * gl + r) * DOUT + nt * 16 + cl] = v;
            }

        t = tn;
    }
}

extern "C" void kernel_launch(void* const* d_in, const int* in_sizes, int n_in,
                              void* d_out, int out_size, void* d_ws, size_t ws_size,
                              hipStream_t stream)
{
    const float* in = (const float*)d_in[0];
    const float* W1 = (const float*)d_in[1];
    const float* b1 = (const float*)d_in[2];
    const float* W2 = (const float*)d_in[3];
    const float* b2 = (const float*)d_in[4];
    const float* W3 = (const float*)d_in[5];
    const float* b3 = (const float*)d_in[6];
    float* out = (float*)d_out;
    const int M = in_sizes[0] / DIN;   // 524288 rows

    dim3 grid(512), block(256);
    hipLaunchKernelGGL(linenet_mfma, grid, block, 0, stream,
                       in, W1, b1, W2, b2, W3, b3, out, M);
}

// Round 2
// 43.854 us; speedup vs baseline: 1.1382x; 1.1382x over previous
//
#include <hip/hip_runtime.h>

typedef float f32x4 __attribute__((ext_vector_type(4)));
typedef short s16x8 __attribute__((ext_vector_type(8)));
typedef unsigned int u32;

#define DIN 24
#define DH1 64
#define DH2 128
#define DOUT 64
// LDS row strides (bf16 elems). Word-stride ≡ 4 (mod 32) -> b32/b64 writes
// land 2-way max (free); 16B-multiple rows keep ds_read_b128 aligned.
#define S1 72
#define S2 136

// f32 -> bf16 bits, RNE (setup-path only)
static __device__ __forceinline__ unsigned short f2bf(float f) {
    u32 u = __builtin_bit_cast(u32, f);
    u += 0x7FFFu + ((u >> 16) & 1u);
    return (unsigned short)(u >> 16);
}

// packed f32x2 -> bf16x2 in one VALU op (guide T12: no builtin, asm ok)
static __device__ __forceinline__ u32 cvtpk(float lo, float hi) {
    u32 r;
    asm("v_cvt_pk_bf16_f32 %0, %1, %2" : "=v"(r) : "v"(lo), "v"(hi));
    return r;
}

__global__ __launch_bounds__(256, 2) void linenet_mfma_t(
    const float* __restrict__ in,
    const float* __restrict__ W1, const float* __restrict__ b1,
    const float* __restrict__ W2, const float* __restrict__ b2,
    const float* __restrict__ W3, const float* __restrict__ b3,
    float* __restrict__ out, int M)
{
    // per-wave private h^T staging: h1t[x-row][feature], row stride S1/S2
    __shared__ __align__(16) unsigned short h1lds[4][1152];  // need <=1143
    __shared__ __align__(16) unsigned short h2lds[4][2176];  // need <=2167

    const int tid  = threadIdx.x;
    const int wave = tid >> 6, lane = tid & 63;
    const int gl = lane >> 4, cl = lane & 15;

    // ---- W^T fragments as MFMA A-operands (VGPR-resident) ----
    // lane holds A[row = 16*tile + cl][k = 8*gl + j]
    s16x8 w1tf[4];                       // W1^T [64x32], k=24 = b1 bias row
    #pragma unroll
    for (int nt = 0; nt < 4; ++nt)
        #pragma unroll
        for (int j = 0; j < 8; ++j) {
            const int k = 8 * gl + j;
            unsigned short v = 0;
            if (k < DIN)       v = f2bf(W1[k * DH1 + nt * 16 + cl]);
            else if (k == DIN) v = f2bf(b1[nt * 16 + cl]);
            w1tf[nt][j] = (short)v;
        }
    s16x8 w2tf[8][2];                    // W2^T [128x64]
    #pragma unroll
    for (int mt = 0; mt < 8; ++mt)
        #pragma unroll
        for (int ks = 0; ks < 2; ++ks)
            #pragma unroll
            for (int j = 0; j < 8; ++j)
                w2tf[mt][ks][j] =
                    (short)f2bf(W2[(32 * ks + 8 * gl + j) * DH2 + mt * 16 + cl]);
    s16x8 w3tf[4][4];                    // W3^T [64x128]
    #pragma unroll
    for (int nt = 0; nt < 4; ++nt)
        #pragma unroll
        for (int ks = 0; ks < 4; ++ks)
            #pragma unroll
            for (int j = 0; j < 8; ++j)
                w3tf[nt][ks][j] =
                    (short)f2bf(W3[(32 * ks + 8 * gl + j) * DOUT + nt * 16 + cl]);

    // biases for layers 2/3: per-lane features 16*t + 4*gl + {0..3}
    f32x4 b2v4[8], b3v4[4];
    #pragma unroll
    for (int mt = 0; mt < 8; ++mt) b2v4[mt] = *(const f32x4*)&b2[16 * mt + 4 * gl];
    #pragma unroll
    for (int nt = 0; nt < 4; ++nt) b3v4[nt] = *(const f32x4*)&b3[16 * nt + 4 * gl];

    unsigned short* const h1p = &h1lds[wave][0];
    unsigned short* const h2p = &h2lds[wave][0];

    const int NT = M / 16;
    const int nw = (int)gridDim.x * 4;
    int t = (int)blockIdx.x * 4 + wave;
    if (t >= NT) return;

    // x^T B-frag: lane holds B[k = 8*gl + j][col = x-row = cl].
    // gl==3 covers k=24..31: k=24 must be 1.0 (bias), rest multiply w1tf zeros.
    const int goff = (gl < 3) ? 8 * gl : 0;      // gl3 loads row head (finite)
    const int loff = cl * DIN + goff;

    f32x4 pf0, pf1;
    {
        const float* p = in + (size_t)t * (16 * DIN) + loff;
        pf0 = *(const f32x4*)p;
        pf1 = *(const f32x4*)(p + 4);
    }

    const f32x4 zac = {0.f, 0.f, 0.f, 0.f};

    while (t < NT) {
        // ---- build x^T fragment from prefetched registers ----
        u32 a1w[4];
        a1w[0] = cvtpk(pf0[0], pf0[1]);
        a1w[1] = cvtpk(pf0[2], pf0[3]);
        a1w[2] = cvtpk(pf1[0], pf1[1]);
        a1w[3] = cvtpk(pf1[2], pf1[3]);
        if (gl == 3) a1w[0] = 0x00003F80u;       // k=24 -> bf16(1.0), k=25 -> 0
        s16x8 a1;
        #pragma unroll
        for (int p = 0; p < 4; ++p) {
            a1[2 * p]     = (short)(a1w[p] & 0xFFFFu);
            a1[2 * p + 1] = (short)(a1w[p] >> 16);
        }

        // ---- prefetch next tile ----
        const int tn = t + nw;
        {
            const int tc = (tn < NT) ? tn : t;
            const float* p = in + (size_t)tc * (16 * DIN) + loff;
            pf0 = *(const f32x4*)p;
            pf1 = *(const f32x4*)(p + 4);
        }

        // ---- layer 1 (transposed): h1^T = W1^T * x^T  (bias via k=24) ----
        f32x4 acc1[4];
        #pragma unroll
        for (int nt = 0; nt < 4; ++nt)
            acc1[nt] = __builtin_amdgcn_mfma_f32_16x16x32_bf16(w1tf[nt], a1, zac, 0, 0, 0);

        // relu + pack pairs (features 16nt+4gl+{0,1,2,3} contiguous) -> LDS
        #pragma unroll
        for (int nt = 0; nt < 4; ++nt) {
            const float v0 = fmaxf(acc1[nt][0], 0.f), v1 = fmaxf(acc1[nt][1], 0.f);
            const float v2 = fmaxf(acc1[nt][2], 0.f), v3 = fmaxf(acc1[nt][3], 0.f);
            u32* w = (u32*)&h1p[cl * S1 + 16 * nt + 4 * gl];
            w[0] = cvtpk(v0, v1);
            w[1] = cvtpk(v2, v3);
        }

        // ---- layer 2 (transposed): h2^T = W2^T * h1^T ----
        s16x8 bh1[2];
        bh1[0] = *(const s16x8*)&h1p[cl * S1 + 0  + 8 * gl];
        bh1[1] = *(const s16x8*)&h1p[cl * S1 + 32 + 8 * gl];
        f32x4 acc2[8];
        #pragma unroll
        for (int mt = 0; mt < 8; ++mt)
            acc2[mt] = __builtin_amdgcn_mfma_f32_16x16x32_bf16(w2tf[mt][0], bh1[0], zac, 0, 0, 0);
        #pragma unroll
        for (int mt = 0; mt < 8; ++mt)
            acc2[mt] = __builtin_amdgcn_mfma_f32_16x16x32_bf16(w2tf[mt][1], bh1[1], acc2[mt], 0, 0, 0);

        #pragma unroll
        for (int mt = 0; mt < 8; ++mt) {
            const f32x4 s = acc2[mt] + b2v4[mt];
            const float v0 = fmaxf(s[0], 0.f), v1 = fmaxf(s[1], 0.f);
            const float v2 = fmaxf(s[2], 0.f), v3 = fmaxf(s[3], 0.f);
            u32* w = (u32*)&h2p[cl * S2 + 16 * mt + 4 * gl];
            w[0] = cvtpk(v0, v1);
            w[1] = cvtpk(v2, v3);
        }

        // ---- layer 3 (transposed): out^T = W3^T * h2^T ----
        f32x4 acc3[4];
        #pragma unroll
        for (int ks = 0; ks < 4; ++ks) {
            const s16x8 bh2 = *(const s16x8*)&h2p[cl * S2 + 32 * ks + 8 * gl];
            #pragma unroll
            for (int nt = 0; nt < 4; ++nt)
                acc3[nt] = __builtin_amdgcn_mfma_f32_16x16x32_bf16(
                    w3tf[nt][ks], bh2, (ks == 0) ? zac : acc3[nt], 0, 0, 0);
        }

        // ---- epilogue: bias + relu, coalesced f32x4 stores ----
        float* const ob = out + (size_t)t * (16 * DOUT) + (size_t)cl * DOUT;
        #pragma unroll
        for (int nt = 0; nt < 4; ++nt) {
            const f32x4 s = acc3[nt] + b3v4[nt];
            f32x4 v;
            v[0] = fmaxf(s[0], 0.f); v[1] = fmaxf(s[1], 0.f);
            v[2] = fmaxf(s[2], 0.f); v[3] = fmaxf(s[3], 0.f);
            *(f32x4*)&ob[16 * nt + 4 * gl] = v;
        }

        t = tn;
    }
}

extern "C" void kernel_launch(void* const* d_in, const int* in_sizes, int n_in,
                              void* d_out, int out_size, void* d_ws, size_t ws_size,
                              hipStream_t stream)
{
    const float* in = (const float*)d_in[0];
    const float* W1 = (const float*)d_in[1];
    const float* b1 = (const float*)d_in[2];
    const float* W2 = (const float*)d_in[3];
    const float* b2 = (const float*)d_in[4];
    const float* W3 = (const float*)d_in[5];
    const float* b3 = (const float*)d_in[6];
    float* out = (float*)d_out;
    const int M = in_sizes[0] / DIN;

    dim3 grid(512), block(256);
    hipLaunchKernelGGL(linenet_mfma_t, grid, block, 0, stream,
                       in, W1, b1, W2, b2, W3, b3, out, M);
}